// Round 1
// baseline (136.889 us; speedup 1.0000x reference)
//
#include <hip/hip_runtime.h>

// Sparse 3D conv (K=3, stride=2, pad=1) scatter-add into dense output.
// Inputs: features [N,32] f32, W [3,3,3,32,64] f32, coors [N,4] i32 (b,z,y,x),
//         batch_size scalar (unused on device; output is pre-sized).
// Output: [B,64,64,64,64] f32, flat.

#define CIN    32
#define COUT   64
#define OUTD   64
#define PADV   1
#define NPTS   128   // points per block

__global__ __launch_bounds__(256, 4) void spconv_scatter(
    const float* __restrict__ feats,
    const float* __restrict__ Wt,
    const int*   __restrict__ coors,
    float*       __restrict__ out,
    int N)
{
    __shared__ float sf[NPTS][CIN];   // 16 KB features
    __shared__ int   sc[NPTS][4];     // 2 KB coords (b,z,y,x)
    __shared__ int   vf[NPTS];        // flat out index or -1, per current offset

    const int tid = threadIdx.x;
    const int ch  = tid & 63;         // output channel
    const int wv  = tid >> 6;         // wave id 0..3

    const int base = blockIdx.x * NPTS;
    const int npts = min(NPTS, N - base);
    if (npts <= 0) return;

    // Stage features (coalesced, contiguous)
    for (int i = tid; i < npts * CIN; i += 256)
        sf[0][i] = feats[base * CIN + i];
    // Stage coords
    for (int i = tid; i < npts * 4; i += 256)
        ((int*)sc)[i] = coors[base * 4 + i];
    __syncthreads();

    for (int off = 0; off < 27; ++off) {
        const int kz = off / 9, ky = (off / 3) % 3, kx = off % 3;

        // Per-point validity + flat output index for this offset (threads 0..npts-1)
        if (tid < npts) {
            const int p  = tid;
            const int nz = sc[p][1] + PADV - kz;
            const int ny = sc[p][2] + PADV - ky;
            const int nx = sc[p][3] + PADV - kx;
            const int m  = nz | ny | nx;
            const int oz = nz >> 1, oy = ny >> 1, ox = nx >> 1;
            // all non-negative, all even, all < OUTD
            const bool v = ((m & 0x80000001) == 0) &&
                           (oz < OUTD) && (oy < OUTD) && (ox < OUTD);
            vf[p] = v ? (((sc[p][0] * OUTD + oz) * OUTD + oy) * OUTD + ox) : -1;
        }

        // Hoist this offset's W column (fixed ch) into registers — coalesced
        const float* wp = Wt + off * (CIN * COUT) + ch;
        float w[CIN];
        #pragma unroll
        for (int c = 0; c < CIN; ++c) w[c] = wp[c * COUT];

        __syncthreads();

        // Each wave owns points p ≡ wv (mod 4); all 64 lanes = 64 output channels
        for (int p = wv; p < npts; p += 4) {
            const int f = vf[p];
            if (f >= 0) {
                float acc = 0.f;
                #pragma unroll
                for (int c = 0; c < CIN; ++c) acc += sf[p][c] * w[c];
                atomicAdd(&out[(size_t)f * COUT + ch], acc);
            }
        }
        __syncthreads();
    }
}

extern "C" void kernel_launch(void* const* d_in, const int* in_sizes, int n_in,
                              void* d_out, int out_size, void* d_ws, size_t ws_size,
                              hipStream_t stream) {
    const float* feats = (const float*)d_in[0];
    const float* Wt    = (const float*)d_in[1];
    const int*   coors = (const int*)d_in[2];
    float*       out   = (float*)d_out;

    const int N = in_sizes[0] / CIN;

    // Zero the dense output (async memset is graph-capture safe)
    hipMemsetAsync(d_out, 0, (size_t)out_size * sizeof(float), stream);

    const int blocks = (N + NPTS - 1) / NPTS;
    spconv_scatter<<<blocks, 256, 0, stream>>>(feats, Wt, coors, out, N);
}